// Round 3
// baseline (336.432 us; speedup 1.0000x reference)
//
#include <hip/hip_runtime.h>
#include <hip/hip_bf16.h>
#include <hip/hip_fp16.h>
#include <string.h>

#define C_DIM 64
#define M_DIM 8
#define O_DIM 64

typedef _Float16 h8 __attribute__((ext_vector_type(8)));
typedef _Float16 h2v __attribute__((ext_vector_type(2)));
typedef float f32x4 __attribute__((ext_vector_type(4)));

union HU { unsigned int u; h2v h; };

__device__ __forceinline__ unsigned int packh2(float a, float b) {
    HU x;
    x.h[0] = (_Float16)a;
    x.h[1] = (_Float16)b;
    return x.u;
}

// xu[v][m] = sum_c data[v][c] * u[c][m]  (fp32, feeds softmax)
__global__ void xu_kernel(const float* __restrict__ data, const float* __restrict__ u,
                          float* __restrict__ xu, int V) {
    int t = blockIdx.x * blockDim.x + threadIdx.x;
    if (t >= V * M_DIM) return;
    int v = t >> 3, m = t & 7;
    const float* dr = data + (size_t)v * C_DIM;
    float s = 0.f;
#pragma unroll
    for (int c = 0; c < C_DIM; ++c) s = fmaf(dr[c], u[c * M_DIM + m], s);
    xu[t] = s;
}

// data (fp32) -> f16 copy, RNE
__global__ void datah_kernel(const float* __restrict__ data,
                             unsigned short* __restrict__ dh, int n4) {
    int t = blockIdx.x * blockDim.x + threadIdx.x;
    if (t >= n4) return;
    f32x4 x = *(const f32x4*)&data[(size_t)t * 4];
    ushort2 o01, o23;
    HU a, b;
    a.h[0] = (_Float16)x[0]; a.h[1] = (_Float16)x[1];
    b.h[0] = (_Float16)x[2]; b.h[1] = (_Float16)x[3];
    uint2 o = {a.u, b.u};
    *(uint2*)&dh[(size_t)t * 4] = o;
    (void)o01; (void)o23;
}

// Repack var_w [M,C,O] into MFMA B-fragment order (f16):
// bfrag[((kt*4+nt)*64 + lane)*8 + j] = f16( Wflat[kt*32 + (lane>>4)*8 + j][nt*16 + (lane&15)] )
__global__ void wb_kernel(const float* __restrict__ w, _Float16* __restrict__ bfrag) {
    int t = blockIdx.x * blockDim.x + threadIdx.x;
    if (t >= 16 * 4 * 64) return;
    int kt = t >> 8;
    int rem = t & 255;
    int nt = rem >> 6;
    int lane = rem & 63;
    int quad = lane >> 4;
    int n = nt * 16 + (lane & 15);
#pragma unroll
    for (int j = 0; j < 8; ++j) {
        int k = kt * 32 + quad * 8 + j;
        bfrag[(size_t)t * 8 + j] = (_Float16)w[k * 64 + n];
    }
}

__global__ void hist_kernel(const int* __restrict__ src, int* __restrict__ counts, int E) {
    int e = blockIdx.x * blockDim.x + threadIdx.x;
    if (e < E) atomicAdd(&counts[src[e]], 1);
}

// 3-phase exclusive scan over counts[V] -> offsets[V]
__global__ void scan_a(const int* __restrict__ counts, int* __restrict__ incl,
                       int* __restrict__ bsums, int V) {
    __shared__ int s[1024];
    int g = blockIdx.x * 1024 + threadIdx.x;
    int x = (g < V) ? counts[g] : 0;
    s[threadIdx.x] = x;
    __syncthreads();
    for (int off = 1; off < 1024; off <<= 1) {
        int add = (threadIdx.x >= off) ? s[threadIdx.x - off] : 0;
        __syncthreads();
        s[threadIdx.x] += add;
        __syncthreads();
    }
    if (g < V) incl[g] = s[threadIdx.x];
    if (threadIdx.x == 1023) bsums[blockIdx.x] = s[1023];
}

__global__ void scan_b(int* __restrict__ bsums, int nb) {
    if (blockIdx.x == 0 && threadIdx.x == 0) {
        int r = 0;
        for (int i = 0; i < nb; ++i) { r += bsums[i]; bsums[i] = r; }
    }
}

__global__ void scan_c(const int* __restrict__ counts, const int* __restrict__ incl,
                       const int* __restrict__ bsums, int* __restrict__ offsets, int V) {
    int g = blockIdx.x * 1024 + threadIdx.x;
    if (g >= V) return;
    int base = (blockIdx.x > 0) ? bsums[blockIdx.x - 1] : 0;
    offsets[g] = base + incl[g] - counts[g];
}

// Per edge: softmax gate * weight -> f16x8, packed with dst into one 32 B
// sector-aligned record, scattered into CSR slot via two full int4 stores.
// Record words: [j, q01, q23, q45, q67, 0, 0, 0]
__global__ __launch_bounds__(256) void gate_scatter_kernel(
    const int* __restrict__ src, const int* __restrict__ dst,
    const float* __restrict__ wt, const float* __restrict__ xu,
    const float* __restrict__ vc, const int* __restrict__ offsets,
    int* __restrict__ cursor, int* __restrict__ recs, int E) {
    int e = blockIdx.x * blockDim.x + threadIdx.x;
    if (e >= E) return;
    int s = src[e], j = dst[e];
    float w = wt[e];
    const f32x4* xs = (const f32x4*)(xu + (size_t)s * 8);
    const f32x4* xj = (const f32x4*)(xu + (size_t)j * 8);
    f32x4 s0 = xs[0], s1 = xs[1], j0 = xj[0], j1 = xj[1];
    float lg[8];
    float mx = -1e30f;
#pragma unroll
    for (int m = 0; m < 4; ++m) {
        lg[m] = s0[m] - j0[m] + vc[m];
        lg[m + 4] = s1[m] - j1[m] + vc[m + 4];
    }
#pragma unroll
    for (int m = 0; m < 8; ++m) mx = fmaxf(mx, lg[m]);
    float den = 0.f;
#pragma unroll
    for (int m = 0; m < 8; ++m) {
        lg[m] = __expf(lg[m] - mx);
        den += lg[m];
    }
    float inv = w / den;
#pragma unroll
    for (int m = 0; m < 8; ++m) lg[m] *= inv;

    int pos = offsets[s] + atomicAdd(&cursor[s], 1);
    int4 lo, hi;
    lo.x = j;
    lo.y = packh2(lg[0], lg[1]);
    lo.z = packh2(lg[2], lg[3]);
    lo.w = packh2(lg[4], lg[5]);
    hi.x = packh2(lg[6], lg[7]);
    hi.y = 0; hi.z = 0; hi.w = 0;
    int4* rp = (int4*)(recs + (size_t)pos * 8);
    rp[0] = lo;
    rp[1] = hi;
}

// Fused: per 16-vertex tile, CSR edge accumulation (f16 gather + fma_mix,
// 8-deep MLP) into LDS f16 A-tile, then 16x16x32 f16 MFMA, + bias, store.
#define A_STRIDE 520
__global__ __launch_bounds__(256) void fused_kernel(
    const unsigned short* __restrict__ datah, const int* __restrict__ recs,
    const int* __restrict__ counts, const int* __restrict__ offsets,
    const _Float16* __restrict__ bfragG, const float* __restrict__ bias,
    float* __restrict__ out, int V) {
    __shared__ _Float16 At[16 * A_STRIDE];
    int wave = __builtin_amdgcn_readfirstlane(threadIdx.x >> 6);
    int lane = threadIdx.x & 63;
    int v_base = blockIdx.x * 16;

    for (int i = 0; i < 4; ++i) {
        int row = wave * 4 + i;
        int v = v_base + row;
        float acc[8] = {0.f, 0.f, 0.f, 0.f, 0.f, 0.f, 0.f, 0.f};
        if (v < V) {
            int deg = __builtin_amdgcn_readfirstlane(counts[v]);
            int off = __builtin_amdgcn_readfirstlane(offsets[v]);
            int t = 0;
#define EDGE_BODY(uu)                                                              \
    do {                                                                           \
        HU q01, q23, q45, q67;                                                     \
        q01.u = (unsigned int)ra[uu].y;                                            \
        q23.u = (unsigned int)ra[uu].z;                                            \
        q45.u = (unsigned int)ra[uu].w;                                            \
        q67.u = (unsigned int)rb[uu];                                              \
        float xf = xff[uu];                                                        \
        acc[0] = fmaf((float)q01.h[0], xf, acc[0]);                                \
        acc[1] = fmaf((float)q01.h[1], xf, acc[1]);                                \
        acc[2] = fmaf((float)q23.h[0], xf, acc[2]);                                \
        acc[3] = fmaf((float)q23.h[1], xf, acc[3]);                                \
        acc[4] = fmaf((float)q45.h[0], xf, acc[4]);                                \
        acc[5] = fmaf((float)q45.h[1], xf, acc[5]);                                \
        acc[6] = fmaf((float)q67.h[0], xf, acc[6]);                                \
        acc[7] = fmaf((float)q67.h[1], xf, acc[7]);                                \
    } while (0)

            for (; t + 8 <= deg; t += 8) {
                int4 ra[8];
                int rb[8];
                float xff[8];
#pragma unroll
                for (int u = 0; u < 8; ++u) {
                    const int* rp = recs + (size_t)(off + t + u) * 8;
                    ra[u] = *(const int4*)rp;
                    rb[u] = rp[4];
                }
#pragma unroll
                for (int u = 0; u < 8; ++u) {
                    HU x;
                    x.u = (unsigned int)datah[(size_t)ra[u].x * 64 + lane];
                    xff[u] = (float)x.h[0];
                }
#pragma unroll
                for (int u = 0; u < 8; ++u) EDGE_BODY(u);
            }
            for (; t + 4 <= deg; t += 4) {
                int4 ra[4];
                int rb[4];
                float xff[4];
#pragma unroll
                for (int u = 0; u < 4; ++u) {
                    const int* rp = recs + (size_t)(off + t + u) * 8;
                    ra[u] = *(const int4*)rp;
                    rb[u] = rp[4];
                }
#pragma unroll
                for (int u = 0; u < 4; ++u) {
                    HU x;
                    x.u = (unsigned int)datah[(size_t)ra[u].x * 64 + lane];
                    xff[u] = (float)x.h[0];
                }
#pragma unroll
                for (int u = 0; u < 4; ++u) EDGE_BODY(u);
            }
            for (; t < deg; ++t) {
                int4 ra[1];
                int rb[1];
                float xff[1];
                const int* rp = recs + (size_t)(off + t) * 8;
                ra[0] = *(const int4*)rp;
                rb[0] = rp[4];
                HU x;
                x.u = (unsigned int)datah[(size_t)ra[0].x * 64 + lane];
                xff[0] = (float)x.h[0];
                EDGE_BODY(0);
            }
        }
#pragma unroll
        for (int m = 0; m < 8; ++m) At[row * A_STRIDE + m * 64 + lane] = (_Float16)acc[m];
    }
    __syncthreads();

    // MFMA phase: wave = output column tile
    f32x4 cacc = {0.f, 0.f, 0.f, 0.f};
    int quad = lane >> 4;
    int r16 = lane & 15;
#pragma unroll
    for (int kt = 0; kt < 16; ++kt) {
        h8 a = *(const h8*)&At[r16 * A_STRIDE + kt * 32 + quad * 8];
        h8 b = *(const h8*)&bfragG[((size_t)(kt * 4 + wave) * 64 + lane) * 8];
        cacc = __builtin_amdgcn_mfma_f32_16x16x32_f16(a, b, cacc, 0, 0, 0);
    }
#pragma unroll
    for (int r = 0; r < 4; ++r) {
        int row = quad * 4 + r;
        int v = v_base + row;
        if (v < V) {
            int o = wave * 16 + r16;
            out[(size_t)v * 64 + o] = cacc[r] + bias[o];
        }
    }
}

extern "C" void kernel_launch(void* const* d_in, const int* in_sizes, int n_in,
                              void* d_out, int out_size, void* d_ws, size_t ws_size,
                              hipStream_t stream) {
    const float* data  = (const float*)d_in[0];
    const int*   esrc  = (const int*)d_in[1];
    const int*   edst  = (const int*)d_in[2];
    const float* ew    = (const float*)d_in[3];
    const float* var_u = (const float*)d_in[4];
    const float* var_c = (const float*)d_in[5];
    const float* var_w = (const float*)d_in[6];
    const float* var_b = (const float*)d_in[7];
    float* out = (float*)d_out;

    int V = in_sizes[0] / C_DIM;
    int E = in_sizes[1];

    char* ws = (char*)d_ws;
    size_t off = 0;
    auto alloc = [&](size_t bytes) -> void* {
        void* p = ws + off;
        off = (off + bytes + 255) & ~(size_t)255;
        return p;
    };
    float*     xu      = (float*)alloc((size_t)V * 8 * 4);
    int*       cc      = (int*)alloc((size_t)V * 2 * 4);   // counts | cursor
    int*       counts  = cc;
    int*       cursor  = cc + V;
    int*       offsets = (int*)alloc((size_t)V * 4);
    int*       incl    = (int*)alloc((size_t)V * 4);
    int*       bsums   = (int*)alloc(4096);
    int*       recs    = (int*)alloc((size_t)E * 32);       // 32 B records
    _Float16*  bfrag   = (_Float16*)alloc((size_t)512 * 64 * 2);
    unsigned short* datah = (unsigned short*)alloc((size_t)V * 64 * 2);

    hipMemsetAsync(cc, 0, (size_t)V * 2 * 4, stream);

    xu_kernel<<<(V * M_DIM + 255) / 256, 256, 0, stream>>>(data, var_u, xu, V);
    datah_kernel<<<(V * 16 + 255) / 256, 256, 0, stream>>>(data, datah, V * 16);
    wb_kernel<<<16, 256, 0, stream>>>(var_w, bfrag);
    hist_kernel<<<(E + 255) / 256, 256, 0, stream>>>(esrc, counts, E);

    int nb = (V + 1023) / 1024;
    scan_a<<<nb, 1024, 0, stream>>>(counts, incl, bsums, V);
    scan_b<<<1, 64, 0, stream>>>(bsums, nb);
    scan_c<<<nb, 1024, 0, stream>>>(counts, incl, bsums, offsets, V);

    gate_scatter_kernel<<<(E + 255) / 256, 256, 0, stream>>>(esrc, edst, ew, xu, var_c,
                                                             offsets, cursor, recs, E);
    fused_kernel<<<(V + 15) / 16, 256, 0, stream>>>(datah, recs, counts, offsets,
                                                    bfrag, var_b, out, V);
}